// Round 12
// baseline (354.613 us; speedup 1.0000x reference)
//
#include <hip/hip_runtime.h>

// GraphDecoder (NRI) — round 21: R20 fused kernel, barrier-reset fixed.
// R20 post-mortem: absmax 44 -> 30 = kernel RAN, phase C raced. Root cause
// found by inspection: bar[32] is byte offset 128, but the per-replay
// hipMemsetAsync cleared only 128 bytes (indices 0..31) -> barrier-2 counter
// never reset -> >=512 from launch 2 onward -> barrier-2 no-op -> phase C
// read aggb before remote blocks wrote it. Barrier-1 (bar[0], reset) WORKED:
// phases A->B coherent, no spin stall. Fix: memset 256 bytes. Everything
// else byte-identical to R20 (bodies = proven R16/R17 kernels).
// Co-residency: bounds(256,3) => <=170 regs (edge body 148 proven), LDS
// 37888 => 3 blocks/CU => capacity 768 >= grid 512. Bounded spin => clean
// failure, not hang. B=32, N=64, F=128, K=4, H=M=NH=256, E=4032.

#define B_ 32
#define N_ 64
#define F_ 128
#define K_ 4
#define E_ 4032

#define WS_W2T 0u
#define WS_R   524288u
#define WS_S   4718592u
#define WS_AGG 8912896u
#define WS_BAR 9961472u   // barrier counters at bytes 0 and 128; 256B reset

typedef unsigned short u16;
typedef u16    u16x4  __attribute__((ext_vector_type(4)));
typedef u16    u16x8  __attribute__((ext_vector_type(8)));
typedef __bf16 bf16x8 __attribute__((ext_vector_type(8)));
typedef float  f32x4  __attribute__((ext_vector_type(4)));
typedef float  f32x16 __attribute__((ext_vector_type(16)));

__device__ __forceinline__ u16 f2bf(float f) {
    unsigned u; __builtin_memcpy(&u, &f, 4);
    return (u16)((u + 0x7FFFu + ((u >> 16) & 1u)) >> 16);
}
__device__ __forceinline__ float bf2f(u16 u) {
    unsigned v = ((unsigned)u) << 16;
    float f; __builtin_memcpy(&f, &v, 4); return f;
}

#define LBAR() do { \
    asm volatile("s_waitcnt lgkmcnt(0)" ::: "memory"); \
    __builtin_amdgcn_s_barrier(); \
    __builtin_amdgcn_sched_barrier(0); \
} while (0)

// device-scope grid barrier for a 512-block co-resident grid.
// Counters zeroed per replay by captured 256B hipMemsetAsync. Bounded spin:
// if the capacity math were wrong we produce a clean failure, not a hang.
__device__ __forceinline__ void gbar(unsigned* c) {
    __syncthreads();
    if (threadIdx.x == 0) {
        __threadfence();                    // release: drain this block's writes
        atomicAdd(c, 1u);
        int guard = 0;
        while (atomicAdd(c, 0u) < 512u && guard < (1 << 22)) {
            __builtin_amdgcn_s_sleep(8);
            ++guard;
        }
    }
    __syncthreads();
    __threadfence();                        // acquire: all threads see remote writes
}

__global__ __launch_bounds__(256, 3) void fused_kernel(
    const float* __restrict__ x, const float* __restrict__ rel,
    const float* __restrict__ W1, const float* __restrict__ b1,
    const float* __restrict__ W2, const float* __restrict__ b2,
    const float* __restrict__ Wo1, const float* __restrict__ bo1,
    const float* __restrict__ Wo2, const float* __restrict__ bo2,
    const float* __restrict__ Wo3, const float* __restrict__ bo3,
    u16* __restrict__ W2t, u16* __restrict__ R, u16* __restrict__ S2,
    u16* __restrict__ aggb, float* __restrict__ out, unsigned* __restrict__ bar)
{
    __shared__ __align__(16) char smem[37888];
    const int tid  = threadIdx.x;
    const int lane = tid & 63;
    const int w    = tid >> 6;
    const int quad = lane >> 4, mloc = lane & 15;
    const int l31  = lane & 31,  lh  = lane >> 5;

    // ================= Phase A: prep (W2t convert + R/S2 tables) =================
    {
        // A1: W2 -> W2t cf layout. Linear coalesced reads, scattered 2B writes.
        {
            unsigned gbase = blockIdx.x * 512u + tid * 2u;
#pragma unroll
            for (int u2 = 0; u2 < 2; ++u2) {
                unsigned gid = gbase + u2;
                unsigned n = gid & 255u, kk = (gid >> 8) & 255u, k = gid >> 16;
                unsigned dst = (k * 8u + (kk >> 5)) * 8192u
                             + (((kk >> 4) & 1u) * 2u + ((kk >> 3) & 1u)) * 2048u
                             + n * 8u + (kk & 7u);
                W2t[dst] = f2bf(W2[gid]);
            }
        }
        // A2: R/S2. 512 blocks = (k, half, b, ch); ch covers 4 c-chunks.
        u16* ldsA = (u16*)smem;            // 64*136 u16
        u16* ldsW = (u16*)(smem + 17408);  // 32*136 u16
        const int bx = blockIdx.x;
        const int k = bx >> 7, half = (bx >> 6) & 1, b = (bx >> 1) & 31, ch = bx & 1;

        for (int idx = tid; idx < 2048; idx += 256) {
            int row = idx >> 5, c4 = idx & 31;
            f32x4 v = *(const f32x4*)&x[(b * 64 + row) * 128 + c4 * 4];
            u16x4 o;
#pragma unroll
            for (int e = 0; e < 4; ++e) o[e] = f2bf(v[e]);
            *(u16x4*)&ldsA[row * 136 + c4 * 4] = o;
        }
        __syncthreads();

        bf16x8 aF[4];
#pragma unroll
        for (int ks = 0; ks < 4; ++ks)
            aF[ks] = *(const bf16x8*)&ldsA[(w * 16 + mloc) * 136 + quad * 8 + ks * 32];

        u16* dst = half ? S2 : R;
        for (int c = ch * 4; c < ch * 4 + 4; ++c) {
            __syncthreads();
            for (int idx = tid; idx < 4096; idx += 256) {
                int n = idx & 31, f = idx >> 5;
                ldsW[n * 136 + f] = f2bf(W1[(k * 256 + half * 128 + f) * 256 + c * 32 + n]);
            }
            __syncthreads();
#pragma unroll
            for (int nt = 0; nt < 2; ++nt) {
                f32x4 acc = (f32x4){0.f, 0.f, 0.f, 0.f};
                const int boff = (nt * 16 + mloc) * 136 + quad * 8;
#pragma unroll
                for (int ks = 0; ks < 4; ++ks)
                    acc = __builtin_amdgcn_mfma_f32_16x16x32_bf16(
                        aF[ks], *(const bf16x8*)&ldsW[boff + ks * 32], acc, 0, 0, 0);
                const int n = c * 32 + nt * 16 + mloc;
                const float bias = half ? 0.f : b1[k * 256 + n];
#pragma unroll
                for (int r = 0; r < 4; ++r) {
                    int row = w * 16 + quad * 4 + r;
                    if (half) {
                        dst[((size_t)((k * 8 + c) * 2048 + b * 64 + row)) * 32 + nt * 16 + mloc]
                            = f2bf(acc[r] + bias);
                    } else {
                        dst[((size_t)(k * 2048 + b * 64 + row)) * 256 + n] = f2bf(acc[r] + bias);
                    }
                }
            }
        }
    }
    gbar(&bar[0]);

    // ================= Phase B: edge (4 receivers per block) =================
    {
        u16  (*Hs)[64][8] = (u16(*)[64][8])smem;                 // 32KB
        float (*Rf)[256]  = (float(*)[256])(smem + 32768);       // 4KB
        float (*rtS)[64]  = (float(*)[64])(smem + 32768 + 4096); // 1KB
        // XCD mapping: lbid = (xcd)<<6 | slot; b = lbid>>4 -> XCD x hosts b in {4x..4x+3}
        const int lbid = ((blockIdx.x & 7) << 6) | (blockIdx.x >> 3);
        const int b    = lbid >> 4;
        const int g    = lbid & 15;
        const u16* Wb  = W2t + lh * 2048 + (w * 64 + l31) * 8;

        for (int r = 0; r < 4; ++r) {
            const int i = g * 4 + r;
            {   // rtS: self-edge trick
                const int k = tid >> 6, j = tid & 63;
                float v = 0.f;
                if (j != i) v = rel[((size_t)(b * E_) + i * 63 + (j - (j > i))) * 4 + k];
                rtS[k][j] = v;
            }
            {   // Rf
                const int k = tid >> 6, e4 = tid & 63;
                u16x4 t4 = *(const u16x4*)&R[((size_t)(k * 2048 + b * 64 + i)) * 256 + e4 * 4];
#pragma unroll
                for (int e = 0; e < 4; ++e) Rf[k][e4 * 4 + e] = bf2f(t4[e]);
            }
            u16x8 sreg[8];
#pragma unroll
            for (int s = 0; s < 8; ++s)
                sreg[s] = *(const u16x8*)&S2[((size_t)(s * 2048 + b * 64 + lane)) * 32 + w * 8];
            __syncthreads();

            float amsg[2] = {0.f, 0.f};

            for (int kT = 0; kT < 4; ++kT) {
                bf16x8 Bb[2][2][2];
#pragma unroll
                for (int ks2 = 0; ks2 < 2; ++ks2) {
                    const u16* wp = Wb + (size_t)(kT * 8) * 8192 + ks2 * 4096;
                    Bb[0][ks2][0] = *(const bf16x8*)(wp);
                    Bb[0][ks2][1] = *(const bf16x8*)(wp + 256);
                }
#pragma unroll
                for (int s = 0; s < 8; ++s) {
                    const float* rp = &Rf[kT][s * 32 + w * 8];
                    f32x4 r0 = *(const f32x4*)rp, r1 = *(const f32x4*)(rp + 4);
                    bf16x8 o;
#pragma unroll
                    for (int e = 0; e < 4; ++e) {
                        o[e]     = (__bf16)fmaxf(r0[e] + bf2f(sreg[s][e]),     0.f);
                        o[4 + e] = (__bf16)fmaxf(r1[e] + bf2f(sreg[s][4 + e]), 0.f);
                    }
                    *(bf16x8*)&Hs[s * 4 + w][lane][0] = o;
                }
                __syncthreads();

                f32x16 acc[2][2];
#pragma unroll
                for (int mt = 0; mt < 2; ++mt)
#pragma unroll
                    for (int nt = 0; nt < 2; ++nt) acc[mt][nt] = (f32x16)(0.f);

#pragma unroll
                for (int kc = 0; kc < 8; ++kc) {
                    const int cur = kc & 1, nxt = cur ^ 1;
                    if (kc == 0 && kT < 3) {
#pragma unroll
                        for (int s = 0; s < 8; ++s)
                            sreg[s] = *(const u16x8*)&S2[((size_t)(((kT + 1) * 8 + s) * 2048 + b * 64 + lane)) * 32 + w * 8];
                    }
                    if (kc < 7) {
#pragma unroll
                        for (int ks2 = 0; ks2 < 2; ++ks2) {
                            const u16* wp = Wb + (size_t)(kT * 8 + kc + 1) * 8192 + ks2 * 4096;
                            Bb[nxt][ks2][0] = *(const bf16x8*)(wp);
                            Bb[nxt][ks2][1] = *(const bf16x8*)(wp + 256);
                        }
                    }
#pragma unroll
                    for (int ks2 = 0; ks2 < 2; ++ks2) {
                        const int gg = kc * 4 + ks2 * 2 + lh;
                        bf16x8 A0 = *(const bf16x8*)&Hs[gg][l31][0];
                        bf16x8 A1 = *(const bf16x8*)&Hs[gg][32 + l31][0];
                        acc[0][0] = __builtin_amdgcn_mfma_f32_32x32x16_bf16(A0, Bb[cur][ks2][0], acc[0][0], 0, 0, 0);
                        acc[0][1] = __builtin_amdgcn_mfma_f32_32x32x16_bf16(A0, Bb[cur][ks2][1], acc[0][1], 0, 0, 0);
                        acc[1][0] = __builtin_amdgcn_mfma_f32_32x32x16_bf16(A1, Bb[cur][ks2][0], acc[1][0], 0, 0, 0);
                        acc[1][1] = __builtin_amdgcn_mfma_f32_32x32x16_bf16(A1, Bb[cur][ks2][1], acc[1][1], 0, 0, 0);
                    }
                }

#pragma unroll
                for (int nt = 0; nt < 2; ++nt) {
                    const float bias = b2[kT * 256 + w * 64 + nt * 32 + l31];
#pragma unroll
                    for (int mt = 0; mt < 2; ++mt) {
                        float s = 0.f;
#pragma unroll
                        for (int rq = 0; rq < 4; ++rq) {
                            f32x4 rt4 = *(const f32x4*)&rtS[kT][mt * 32 + rq * 8 + 4 * lh];
#pragma unroll
                            for (int e = 0; e < 4; ++e) {
                                float v = acc[mt][nt][rq * 4 + e] + bias;
                                v = v > 0.f ? v : 0.f;
                                s += rt4[e] * v;
                            }
                        }
                        amsg[nt] += s;
                    }
                }
                __syncthreads();
            }

#pragma unroll
            for (int nt = 0; nt < 2; ++nt) {
                float s = amsg[nt] + __shfl_xor(amsg[nt], 32);
                if (lh == 0)
                    aggb[(size_t)(b * 64 + i) * 256 + w * 64 + nt * 32 + l31] = f2bf(s);
            }
        }
    }
    gbar(&bar[32]);

    // ================= Phase C: output MLP (blocks 0..127, 16 rows each) =================
    if (blockIdx.x < 128) {
        u16* p1S = (u16*)smem;            // 16*264
        u16* p2S = (u16*)(smem + 8448);   // 16*264
        const int row0 = blockIdx.x * 16;

        {   // L1: K=384 (12 chunks), N=256, aug=[x|agg]
            f32x4 acc[4];
#pragma unroll
            for (int nt = 0; nt < 4; ++nt) acc[nt] = (f32x4){0.f, 0.f, 0.f, 0.f};
            for (int kk = 0; kk < 12; ++kk) {
                bf16x8 aF;
                const int row = row0 + mloc;
                if (kk < 4) {
                    u16x8 t;
#pragma unroll
                    for (int e = 0; e < 8; ++e) t[e] = f2bf(x[row * 128 + kk * 32 + quad * 8 + e]);
                    __builtin_memcpy(&aF, &t, 16);
                } else {
                    aF = *(const bf16x8*)&aggb[(size_t)row * 256 + (kk - 4) * 32 + quad * 8];
                }
#pragma unroll
                for (int nt = 0; nt < 4; ++nt) {
                    const int n = w * 64 + nt * 16 + mloc;
                    u16x8 t;
#pragma unroll
                    for (int e = 0; e < 8; ++e)
                        t[e] = f2bf(Wo1[(kk * 32 + quad * 8 + e) * 256 + n]);
                    bf16x8 bF;
                    __builtin_memcpy(&bF, &t, 16);
                    acc[nt] = __builtin_amdgcn_mfma_f32_16x16x32_bf16(aF, bF, acc[nt], 0, 0, 0);
                }
            }
#pragma unroll
            for (int nt = 0; nt < 4; ++nt) {
                const int n = w * 64 + nt * 16 + mloc;
                const float bias = bo1[n];
#pragma unroll
                for (int r = 0; r < 4; ++r) {
                    float v = acc[nt][r] + bias;
                    p1S[(quad * 4 + r) * 264 + n] = f2bf(v > 0.f ? v : 0.f);
                }
            }
        }
        LBAR();
        {   // L2: K=256 (8 chunks), N=256
            f32x4 acc[4];
#pragma unroll
            for (int nt = 0; nt < 4; ++nt) acc[nt] = (f32x4){0.f, 0.f, 0.f, 0.f};
            for (int kk = 0; kk < 8; ++kk) {
                bf16x8 aF = *(const bf16x8*)&p1S[mloc * 264 + kk * 32 + quad * 8];
#pragma unroll
                for (int nt = 0; nt < 4; ++nt) {
                    const int n = w * 64 + nt * 16 + mloc;
                    u16x8 t;
#pragma unroll
                    for (int e = 0; e < 8; ++e)
                        t[e] = f2bf(Wo2[(kk * 32 + quad * 8 + e) * 256 + n]);
                    bf16x8 bF;
                    __builtin_memcpy(&bF, &t, 16);
                    acc[nt] = __builtin_amdgcn_mfma_f32_16x16x32_bf16(aF, bF, acc[nt], 0, 0, 0);
                }
            }
#pragma unroll
            for (int nt = 0; nt < 4; ++nt) {
                const int n = w * 64 + nt * 16 + mloc;
                const float bias = bo2[n];
#pragma unroll
                for (int r = 0; r < 4; ++r) {
                    float v = acc[nt][r] + bias;
                    p2S[(quad * 4 + r) * 264 + n] = f2bf(v > 0.f ? v : 0.f);
                }
            }
        }
        LBAR();
        {   // L3: K=256 (8 chunks), N=128, residual
            f32x4 acc[2];
#pragma unroll
            for (int nt = 0; nt < 2; ++nt) acc[nt] = (f32x4){0.f, 0.f, 0.f, 0.f};
            for (int kk = 0; kk < 8; ++kk) {
                bf16x8 aF = *(const bf16x8*)&p2S[mloc * 264 + kk * 32 + quad * 8];
#pragma unroll
                for (int nt = 0; nt < 2; ++nt) {
                    const int n = w * 32 + nt * 16 + mloc;
                    u16x8 t;
#pragma unroll
                    for (int e = 0; e < 8; ++e)
                        t[e] = f2bf(Wo3[(kk * 32 + quad * 8 + e) * 128 + n]);
                    bf16x8 bF;
                    __builtin_memcpy(&bF, &t, 16);
                    acc[nt] = __builtin_amdgcn_mfma_f32_16x16x32_bf16(aF, bF, acc[nt], 0, 0, 0);
                }
            }
#pragma unroll
            for (int nt = 0; nt < 2; ++nt) {
                const int n = w * 32 + nt * 16 + mloc;
                const float bias = bo3[n];
#pragma unroll
                for (int r = 0; r < 4; ++r) {
                    const int grow = row0 + quad * 4 + r;
                    out[grow * 128 + n] = x[grow * 128 + n] + acc[nt][r] + bias;
                }
            }
        }
    }
}

extern "C" void kernel_launch(void* const* d_in, const int* in_sizes, int n_in,
                              void* d_out, int out_size, void* d_ws, size_t ws_size,
                              hipStream_t stream) {
    const float* x   = (const float*)d_in[0];
    const float* rel = (const float*)d_in[1];
    const float* W1  = (const float*)d_in[4];
    const float* b1  = (const float*)d_in[5];
    const float* W2  = (const float*)d_in[6];
    const float* b2  = (const float*)d_in[7];
    const float* Wo1 = (const float*)d_in[8];
    const float* bo1 = (const float*)d_in[9];
    const float* Wo2 = (const float*)d_in[10];
    const float* bo2 = (const float*)d_in[11];
    const float* Wo3 = (const float*)d_in[12];
    const float* bo3 = (const float*)d_in[13];
    float* out = (float*)d_out;

    char* ws = (char*)d_ws;
    u16* W2t  = (u16*)(ws + WS_W2T);
    u16* R    = (u16*)(ws + WS_R);
    u16* S2   = (u16*)(ws + WS_S);
    u16* aggb = (u16*)(ws + WS_AGG);
    unsigned* bar = (unsigned*)(ws + WS_BAR);

    // reset BOTH barrier counters every replay (bar[0] @ byte 0, bar[32] @ byte 128)
    hipMemsetAsync(bar, 0, 256, stream);
    hipLaunchKernelGGL(fused_kernel, dim3(512), dim3(256), 0, stream,
                       x, rel, W1, b1, W2, b2, Wo1, bo1, Wo2, bo2, Wo3, bo3,
                       W2t, R, S2, aggb, out, bar);
}

// Round 13
// 196.066 us; speedup vs baseline: 1.8086x; 1.8086x over previous
//
#include <hip/hip_runtime.h>

// GraphDecoder (NRI) — round 22: REVERT to R17 3-kernel (193.3us proven;
// R21 fused = 300us device — device-barrier L2 flush/invalidate costs ~100us
// of refetch, fusion closed). Increments on proven kernels:
//  - edge13: 3-slot B prefetch (2 kc lookahead, static idx; ~100 VGPR+64 AGPR
//    = 164 <= 170, (256,3) intact).
//  - prep part-2: 1024 blocks x 2 c-chunks (halved serial chain, 2x TLP).
//  - outmlp6: 256 blocks x 8 rows (dup-row trick; 2x CU coverage).
// B=32, N=64, F=128, K=4, H=M=NH=256, E=4032.

#define B_ 32
#define N_ 64
#define F_ 128
#define K_ 4
#define E_ 4032

// ws layout (bytes): total 9,961,472 <= proven 9,994,240
#define WS_W2T 0u
#define WS_R   524288u
#define WS_S   4718592u
#define WS_AGG 8912896u

typedef unsigned short u16;
typedef u16    u16x4  __attribute__((ext_vector_type(4)));
typedef u16    u16x8  __attribute__((ext_vector_type(8)));
typedef __bf16 bf16x8 __attribute__((ext_vector_type(8)));
typedef float  f32x4  __attribute__((ext_vector_type(4)));
typedef float  f32x16 __attribute__((ext_vector_type(16)));

__device__ __forceinline__ u16 f2bf(float f) {
    unsigned u; __builtin_memcpy(&u, &f, 4);
    return (u16)((u + 0x7FFFu + ((u >> 16) & 1u)) >> 16);
}
__device__ __forceinline__ float bf2f(u16 u) {
    unsigned v = ((unsigned)u) << 16;
    float f; __builtin_memcpy(&f, &v, 4); return f;
}

// raw barrier (LDS-only handoff; keeps vmem prefetch in flight)
#define LBAR() do { \
    asm volatile("s_waitcnt lgkmcnt(0)" ::: "memory"); \
    __builtin_amdgcn_s_barrier(); \
    __builtin_amdgcn_sched_barrier(0); \
} while (0)

// ---------------- fused prep (W2 -> cf bf16 chunks) + R/S2 tables ----------------
// S2 kk-chunked: S2[((k*8+kc)*2048 + b*64 + row)*32 + kk_local]  (kc = kk>>5)
__global__ __launch_bounds__(256) void prep_rs_kernel(
    const float* __restrict__ W2, const float* __restrict__ x,
    const float* __restrict__ W1, const float* __restrict__ b1,
    u16* __restrict__ W2t, u16* __restrict__ R, u16* __restrict__ S)
{
    __shared__ u16 ldsA[64 * 136];
    __shared__ u16 ldsW[32 * 136];
    const int tid = threadIdx.x;

    if (blockIdx.x < 1024) {
        // linear read of W2 (coalesced); scattered 2B writes (fire-and-forget).
        // gid = (k*256+kk)*256+n ; kk bits: [7:5]=kc [4]=ks2 [3]=lhh [2:0]=e
        // dst = (k*8+kc)*8192 + (ks2*2+lhh)*2048 + n*8 + e
        unsigned gid = blockIdx.x * 256u + tid;
        unsigned n = gid & 255u, kk = (gid >> 8) & 255u, k = gid >> 16;
        unsigned dst = (k * 8u + (kk >> 5)) * 8192u
                     + ((((kk >> 4) & 1u) * 2u) + ((kk >> 3) & 1u)) * 2048u
                     + n * 8u + (kk & 7u);
        W2t[dst] = f2bf(W2[gid]);
        return;
    }

    // part 2: R/S tables. 1024 blocks: (k, half, b) x ch4; ch covers 2 c-chunks.
    const int lane = tid & 63, w = tid >> 6;
    const int quad = lane >> 4, mloc = lane & 15;
    const int bx = blockIdx.x - 1024;
    const int ch = bx & 3;
    const int bq = bx >> 2;
    const int k = bq >> 6, half = (bq >> 5) & 1, b = bq & 31;

    for (int idx = tid; idx < 2048; idx += 256) {
        int row = idx >> 5, c4 = idx & 31;
        f32x4 v = *(const f32x4*)&x[(b * 64 + row) * 128 + c4 * 4];
        u16x4 o;
#pragma unroll
        for (int e = 0; e < 4; ++e) o[e] = f2bf(v[e]);
        *(u16x4*)&ldsA[row * 136 + c4 * 4] = o;
    }
    __syncthreads();

    bf16x8 aF[4];
#pragma unroll
    for (int ks = 0; ks < 4; ++ks)
        aF[ks] = *(const bf16x8*)&ldsA[(w * 16 + mloc) * 136 + quad * 8 + ks * 32];

    u16* dst = half ? S : R;
    for (int c = ch * 2; c < ch * 2 + 2; ++c) {
        __syncthreads();
        for (int idx = tid; idx < 4096; idx += 256) {
            int n = idx & 31, f = idx >> 5;
            ldsW[n * 136 + f] = f2bf(W1[(k * 256 + half * 128 + f) * 256 + c * 32 + n]);
        }
        __syncthreads();
#pragma unroll
        for (int nt = 0; nt < 2; ++nt) {
            f32x4 acc = (f32x4){0.f, 0.f, 0.f, 0.f};
            const int boff = (nt * 16 + mloc) * 136 + quad * 8;
#pragma unroll
            for (int ks = 0; ks < 4; ++ks)
                acc = __builtin_amdgcn_mfma_f32_16x16x32_bf16(
                    aF[ks], *(const bf16x8*)&ldsW[boff + ks * 32], acc, 0, 0, 0);
            const int n = c * 32 + nt * 16 + mloc;
            const float bias = half ? 0.f : b1[k * 256 + n];
#pragma unroll
            for (int r = 0; r < 4; ++r) {
                int row = w * 16 + quad * 4 + r;
                if (half) {
                    dst[((size_t)((k * 8 + c) * 2048 + b * 64 + row)) * 32 + nt * 16 + mloc]
                        = f2bf(acc[r] + bias);
                } else {
                    dst[((size_t)(k * 2048 + b * 64 + row)) * 256 + n] = f2bf(acc[r] + bias);
                }
            }
        }
    }
}

// ---------------- edge kernel: per-kT staged H + 3-slot B prefetch ----------------
__global__ __launch_bounds__(256, 3) void edge13_kernel(
    const u16* __restrict__ R, const u16* __restrict__ S2,
    const float* __restrict__ rel, const u16* __restrict__ W2t,
    const float* __restrict__ b2, u16* __restrict__ aggb)
{
    __shared__ u16   Hs[32][64][8];   // H tile for one kT: [g=kk-group][row][8kk] — 32KB
    __shared__ float Rf[4][256];      // receiver R rows, f32 — written once
    __shared__ float rtS[4][64];      // rel_type [k][j], self=0 — written once

    const int tid  = threadIdx.x;
    const int lane = tid & 63;
    const int w    = tid >> 6;        // n-quarter (MFMA) AND kk32-subgroup (build)
    const int l31  = lane & 31;
    const int lh   = lane >> 5;
    const int bid  = ((blockIdx.x & 7) << 8) | (blockIdx.x >> 3);
    const int b    = bid >> 6;
    const int i    = bid & 63;        // receiver node

    {
        const int k = tid >> 6, j = tid & 63;
        float v = 0.f;
        if (j != i) v = rel[((size_t)(b * E_) + i * 63 + (j - (j > i))) * 4 + k];
        rtS[k][j] = v;
    }
    {
        const int k = tid >> 6, e4 = tid & 63;
        u16x4 t4 = *(const u16x4*)&R[((size_t)(k * 2048 + b * 64 + i)) * 256 + e4 * 4];
#pragma unroll
        for (int e = 0; e < 4; ++e) Rf[k][e4 * 4 + e] = bf2f(t4[e]);
    }

    u16x8 sreg[8];
#pragma unroll
    for (int s = 0; s < 8; ++s)
        sreg[s] = *(const u16x8*)&S2[((size_t)(s * 2048 + b * 64 + lane)) * 32 + w * 8];

    __syncthreads();

    const u16* Wb = W2t + lh * 2048 + (w * 64 + l31) * 8;

    float amsg[2] = {0.f, 0.f};

    for (int kT = 0; kT < 4; ++kT) {
        // prologue: preload B for kc=0 and kc=1 (latency hides under build+bar)
        bf16x8 Bb[3][2][2];   // [slot = kc%3][ks2][nt] — all indices static
#pragma unroll
        for (int pre = 0; pre < 2; ++pre)
#pragma unroll
            for (int ks2 = 0; ks2 < 2; ++ks2) {
                const u16* wp = Wb + (size_t)(kT * 8 + pre) * 8192 + ks2 * 4096;
                Bb[pre][ks2][0] = *(const bf16x8*)(wp);
                Bb[pre][ks2][1] = *(const bf16x8*)(wp + 256);
            }
        // ---- build H(kT) from sreg: pure VALU, conflict-free writes ----
#pragma unroll
        for (int s = 0; s < 8; ++s) {
            const float* rp = &Rf[kT][s * 32 + w * 8];
            f32x4 r0 = *(const f32x4*)rp, r1 = *(const f32x4*)(rp + 4);
            bf16x8 o;
#pragma unroll
            for (int e = 0; e < 4; ++e) {
                o[e]     = (__bf16)fmaxf(r0[e] + bf2f(sreg[s][e]),     0.f);
                o[4 + e] = (__bf16)fmaxf(r1[e] + bf2f(sreg[s][4 + e]), 0.f);
            }
            *(bf16x8*)&Hs[s * 4 + w][lane][0] = o;
        }
        __syncthreads();

        f32x16 acc[2][2];
#pragma unroll
        for (int mt = 0; mt < 2; ++mt)
#pragma unroll
            for (int nt = 0; nt < 2; ++nt) acc[mt][nt] = (f32x16)(0.f);

#pragma unroll
        for (int kc = 0; kc < 8; ++kc) {
            const int cur = kc % 3;
            // reload sreg for kT+1 (regs dead after build consumed them)
            if (kc == 0 && kT < 3) {
#pragma unroll
                for (int s = 0; s < 8; ++s)
                    sreg[s] = *(const u16x8*)&S2[((size_t)(((kT + 1) * 8 + s) * 2048 + b * 64 + lane)) * 32 + w * 8];
            }
            // prefetch B two kc ahead (slots cycle mod 3)
            if (kc < 6) {
                const int nxt = (kc + 2) % 3;
#pragma unroll
                for (int ks2 = 0; ks2 < 2; ++ks2) {
                    const u16* wp = Wb + (size_t)(kT * 8 + kc + 2) * 8192 + ks2 * 4096;
                    Bb[nxt][ks2][0] = *(const bf16x8*)(wp);
                    Bb[nxt][ks2][1] = *(const bf16x8*)(wp + 256);
                }
            }
#pragma unroll
            for (int ks2 = 0; ks2 < 2; ++ks2) {
                const int g = kc * 4 + ks2 * 2 + lh;
                bf16x8 A0 = *(const bf16x8*)&Hs[g][l31][0];
                bf16x8 A1 = *(const bf16x8*)&Hs[g][32 + l31][0];
                acc[0][0] = __builtin_amdgcn_mfma_f32_32x32x16_bf16(A0, Bb[cur][ks2][0], acc[0][0], 0, 0, 0);
                acc[0][1] = __builtin_amdgcn_mfma_f32_32x32x16_bf16(A0, Bb[cur][ks2][1], acc[0][1], 0, 0, 0);
                acc[1][0] = __builtin_amdgcn_mfma_f32_32x32x16_bf16(A1, Bb[cur][ks2][0], acc[1][0], 0, 0, 0);
                acc[1][1] = __builtin_amdgcn_mfma_f32_32x32x16_bf16(A1, Bb[cur][ks2][1], acc[1][1], 0, 0, 0);
            }
        }

#pragma unroll
        for (int nt = 0; nt < 2; ++nt) {
            const float bias = b2[kT * 256 + w * 64 + nt * 32 + l31];
#pragma unroll
            for (int mt = 0; mt < 2; ++mt) {
                float s = 0.f;
#pragma unroll
                for (int rq = 0; rq < 4; ++rq) {
                    f32x4 rt4 = *(const f32x4*)&rtS[kT][mt * 32 + rq * 8 + 4 * lh];
#pragma unroll
                    for (int e = 0; e < 4; ++e) {
                        float v = acc[mt][nt][rq * 4 + e] + bias;
                        v = v > 0.f ? v : 0.f;
                        s += rt4[e] * v;
                    }
                }
                amsg[nt] += s;
            }
        }
        __syncthreads();
    }

#pragma unroll
    for (int nt = 0; nt < 2; ++nt) {
        float s = amsg[nt] + __shfl_xor(amsg[nt], 32);
        if (lh == 0)
            aggb[(size_t)(b * 64 + i) * 256 + w * 64 + nt * 32 + l31] = f2bf(s);
    }
}

// ---------------- output MLP: 256 blocks x 8 rows, barrier-free layers ----------------
// Dup-row trick: A rows 8..15 duplicate rows 0..7 (C rows 8..15 = dup), only
// quad<2 writes. 2x CU coverage vs 128-block version; B from global f32.
__global__ __launch_bounds__(256) void outmlp6_kernel(
    const float* __restrict__ x, const u16* __restrict__ aggb,
    const float* __restrict__ Wo1, const float* __restrict__ bo1,
    const float* __restrict__ Wo2, const float* __restrict__ bo2,
    const float* __restrict__ Wo3, const float* __restrict__ bo3,
    float* __restrict__ out)
{
    __shared__ u16 p1S[8 * 264];
    __shared__ u16 p2S[8 * 264];
    const int tid = threadIdx.x, lane = tid & 63, w = tid >> 6;   // w = n-quarter
    const int quad = lane >> 4, mloc = lane & 15;
    const int row0 = blockIdx.x * 8;
    const int arow = row0 + (mloc & 7);    // duplicated A row

    {   // ---- L1: K=384 (12 chunks), N=256, aug=[x|agg] ----
        f32x4 acc[4];
#pragma unroll
        for (int nt = 0; nt < 4; ++nt) acc[nt] = (f32x4){0.f, 0.f, 0.f, 0.f};
        for (int kk = 0; kk < 12; ++kk) {
            bf16x8 aF;
            if (kk < 4) {
                u16x8 t;
#pragma unroll
                for (int e = 0; e < 8; ++e) t[e] = f2bf(x[arow * 128 + kk * 32 + quad * 8 + e]);
                __builtin_memcpy(&aF, &t, 16);
            } else {
                aF = *(const bf16x8*)&aggb[(size_t)arow * 256 + (kk - 4) * 32 + quad * 8];
            }
#pragma unroll
            for (int nt = 0; nt < 4; ++nt) {
                const int n = w * 64 + nt * 16 + mloc;
                u16x8 t;
#pragma unroll
                for (int e = 0; e < 8; ++e)
                    t[e] = f2bf(Wo1[(kk * 32 + quad * 8 + e) * 256 + n]);
                bf16x8 bF;
                __builtin_memcpy(&bF, &t, 16);
                acc[nt] = __builtin_amdgcn_mfma_f32_16x16x32_bf16(aF, bF, acc[nt], 0, 0, 0);
            }
        }
#pragma unroll
        for (int nt = 0; nt < 4; ++nt) {
            const int n = w * 64 + nt * 16 + mloc;
            const float bias = bo1[n];
            if (quad < 2) {
#pragma unroll
                for (int r = 0; r < 4; ++r) {
                    float v = acc[nt][r] + bias;
                    p1S[(quad * 4 + r) * 264 + n] = f2bf(v > 0.f ? v : 0.f);
                }
            }
        }
    }
    LBAR();
    {   // ---- L2: K=256 (8 chunks), N=256 ----
        f32x4 acc[4];
#pragma unroll
        for (int nt = 0; nt < 4; ++nt) acc[nt] = (f32x4){0.f, 0.f, 0.f, 0.f};
        for (int kk = 0; kk < 8; ++kk) {
            bf16x8 aF = *(const bf16x8*)&p1S[(mloc & 7) * 264 + kk * 32 + quad * 8];
#pragma unroll
            for (int nt = 0; nt < 4; ++nt) {
                const int n = w * 64 + nt * 16 + mloc;
                u16x8 t;
#pragma unroll
                for (int e = 0; e < 8; ++e)
                    t[e] = f2bf(Wo2[(kk * 32 + quad * 8 + e) * 256 + n]);
                bf16x8 bF;
                __builtin_memcpy(&bF, &t, 16);
                acc[nt] = __builtin_amdgcn_mfma_f32_16x16x32_bf16(aF, bF, acc[nt], 0, 0, 0);
            }
        }
#pragma unroll
        for (int nt = 0; nt < 4; ++nt) {
            const int n = w * 64 + nt * 16 + mloc;
            const float bias = bo2[n];
            if (quad < 2) {
#pragma unroll
                for (int r = 0; r < 4; ++r) {
                    float v = acc[nt][r] + bias;
                    p2S[(quad * 4 + r) * 264 + n] = f2bf(v > 0.f ? v : 0.f);
                }
            }
        }
    }
    LBAR();
    {   // ---- L3: K=256 (8 chunks), N=128, residual ----
        f32x4 acc[2];
#pragma unroll
        for (int nt = 0; nt < 2; ++nt) acc[nt] = (f32x4){0.f, 0.f, 0.f, 0.f};
        for (int kk = 0; kk < 8; ++kk) {
            bf16x8 aF = *(const bf16x8*)&p2S[(mloc & 7) * 264 + kk * 32 + quad * 8];
#pragma unroll
            for (int nt = 0; nt < 2; ++nt) {
                const int n = w * 32 + nt * 16 + mloc;
                u16x8 t;
#pragma unroll
                for (int e = 0; e < 8; ++e)
                    t[e] = f2bf(Wo3[(kk * 32 + quad * 8 + e) * 128 + n]);
                bf16x8 bF;
                __builtin_memcpy(&bF, &t, 16);
                acc[nt] = __builtin_amdgcn_mfma_f32_16x16x32_bf16(aF, bF, acc[nt], 0, 0, 0);
            }
        }
#pragma unroll
        for (int nt = 0; nt < 2; ++nt) {
            const int n = w * 32 + nt * 16 + mloc;
            const float bias = bo3[n];
            if (quad < 2) {
#pragma unroll
                for (int r = 0; r < 4; ++r) {
                    const int grow = row0 + quad * 4 + r;
                    out[grow * 128 + n] = x[grow * 128 + n] + acc[nt][r] + bias;
                }
            }
        }
    }
}

extern "C" void kernel_launch(void* const* d_in, const int* in_sizes, int n_in,
                              void* d_out, int out_size, void* d_ws, size_t ws_size,
                              hipStream_t stream) {
    const float* x   = (const float*)d_in[0];
    const float* rel = (const float*)d_in[1];
    const float* W1  = (const float*)d_in[4];
    const float* b1  = (const float*)d_in[5];
    const float* W2  = (const float*)d_in[6];
    const float* b2  = (const float*)d_in[7];
    const float* Wo1 = (const float*)d_in[8];
    const float* bo1 = (const float*)d_in[9];
    const float* Wo2 = (const float*)d_in[10];
    const float* bo2 = (const float*)d_in[11];
    const float* Wo3 = (const float*)d_in[12];
    const float* bo3 = (const float*)d_in[13];
    float* out = (float*)d_out;

    char* ws = (char*)d_ws;
    u16* W2t  = (u16*)(ws + WS_W2T);
    u16* R    = (u16*)(ws + WS_R);
    u16* S2   = (u16*)(ws + WS_S);
    u16* aggb = (u16*)(ws + WS_AGG);

    prep_rs_kernel<<<2048, 256, 0, stream>>>(W2, x, W1, b1, W2t, R, S2);
    edge13_kernel<<<2048, 256, 0, stream>>>(R, S2, rel, W2t, b2, aggb);
    outmlp6_kernel<<<256, 256, 0, stream>>>(x, aggb, Wo1, bo1, Wo2, bo2, Wo3, bo3, out);
}

// Round 14
// 192.234 us; speedup vs baseline: 1.8447x; 1.0199x over previous
//
#include <hip/hip_runtime.h>

// GraphDecoder (NRI) — round 23: recombine proven parts. R22 attribution:
// edge13 3-slot prefetch REGRESSED (85.4->95.0us, WRITE 1.8->6.3MB = spill,
// tripwire hit) -> revert to byte-exact edge12 (R16/R17-proven 85.4us).
// KEEP R22's prep (part-2 at 1024 blocks x 2 c-chunks) and outmlp6
// (256 blocks x 8 rows, dup-row) — together they cut non-edge 107.9->101.1.
// B=32, N=64, F=128, K=4, H=M=NH=256, E=4032.

#define B_ 32
#define N_ 64
#define F_ 128
#define K_ 4
#define E_ 4032

// ws layout (bytes): total 9,961,472 <= proven 9,994,240
#define WS_W2T 0u
#define WS_R   524288u
#define WS_S   4718592u
#define WS_AGG 8912896u

typedef unsigned short u16;
typedef u16    u16x4  __attribute__((ext_vector_type(4)));
typedef u16    u16x8  __attribute__((ext_vector_type(8)));
typedef __bf16 bf16x8 __attribute__((ext_vector_type(8)));
typedef float  f32x4  __attribute__((ext_vector_type(4)));
typedef float  f32x16 __attribute__((ext_vector_type(16)));

__device__ __forceinline__ u16 f2bf(float f) {
    unsigned u; __builtin_memcpy(&u, &f, 4);
    return (u16)((u + 0x7FFFu + ((u >> 16) & 1u)) >> 16);
}
__device__ __forceinline__ float bf2f(u16 u) {
    unsigned v = ((unsigned)u) << 16;
    float f; __builtin_memcpy(&f, &v, 4); return f;
}

// raw barrier (LDS-only handoff; keeps vmem prefetch in flight)
#define LBAR() do { \
    asm volatile("s_waitcnt lgkmcnt(0)" ::: "memory"); \
    __builtin_amdgcn_s_barrier(); \
    __builtin_amdgcn_sched_barrier(0); \
} while (0)

// ---------------- fused prep (W2 -> cf bf16 chunks) + R/S2 tables ----------------
// S2 kk-chunked: S2[((k*8+kc)*2048 + b*64 + row)*32 + kk_local]  (kc = kk>>5)
__global__ __launch_bounds__(256) void prep_rs_kernel(
    const float* __restrict__ W2, const float* __restrict__ x,
    const float* __restrict__ W1, const float* __restrict__ b1,
    u16* __restrict__ W2t, u16* __restrict__ R, u16* __restrict__ S)
{
    __shared__ u16 ldsA[64 * 136];
    __shared__ u16 ldsW[32 * 136];
    const int tid = threadIdx.x;

    if (blockIdx.x < 1024) {
        // linear read of W2 (coalesced); scattered 2B writes (fire-and-forget).
        // gid = (k*256+kk)*256+n ; kk bits: [7:5]=kc [4]=ks2 [3]=lhh [2:0]=e
        // dst = (k*8+kc)*8192 + (ks2*2+lhh)*2048 + n*8 + e
        unsigned gid = blockIdx.x * 256u + tid;
        unsigned n = gid & 255u, kk = (gid >> 8) & 255u, k = gid >> 16;
        unsigned dst = (k * 8u + (kk >> 5)) * 8192u
                     + ((((kk >> 4) & 1u) * 2u) + ((kk >> 3) & 1u)) * 2048u
                     + n * 8u + (kk & 7u);
        W2t[dst] = f2bf(W2[gid]);
        return;
    }

    // part 2: R/S tables. 1024 blocks: (k, half, b) x ch4; ch covers 2 c-chunks.
    const int lane = tid & 63, w = tid >> 6;
    const int quad = lane >> 4, mloc = lane & 15;
    const int bx = blockIdx.x - 1024;
    const int ch = bx & 3;
    const int bq = bx >> 2;
    const int k = bq >> 6, half = (bq >> 5) & 1, b = bq & 31;

    for (int idx = tid; idx < 2048; idx += 256) {
        int row = idx >> 5, c4 = idx & 31;
        f32x4 v = *(const f32x4*)&x[(b * 64 + row) * 128 + c4 * 4];
        u16x4 o;
#pragma unroll
        for (int e = 0; e < 4; ++e) o[e] = f2bf(v[e]);
        *(u16x4*)&ldsA[row * 136 + c4 * 4] = o;
    }
    __syncthreads();

    bf16x8 aF[4];
#pragma unroll
    for (int ks = 0; ks < 4; ++ks)
        aF[ks] = *(const bf16x8*)&ldsA[(w * 16 + mloc) * 136 + quad * 8 + ks * 32];

    u16* dst = half ? S : R;
    for (int c = ch * 2; c < ch * 2 + 2; ++c) {
        __syncthreads();
        for (int idx = tid; idx < 4096; idx += 256) {
            int n = idx & 31, f = idx >> 5;
            ldsW[n * 136 + f] = f2bf(W1[(k * 256 + half * 128 + f) * 256 + c * 32 + n]);
        }
        __syncthreads();
#pragma unroll
        for (int nt = 0; nt < 2; ++nt) {
            f32x4 acc = (f32x4){0.f, 0.f, 0.f, 0.f};
            const int boff = (nt * 16 + mloc) * 136 + quad * 8;
#pragma unroll
            for (int ks = 0; ks < 4; ++ks)
                acc = __builtin_amdgcn_mfma_f32_16x16x32_bf16(
                    aF[ks], *(const bf16x8*)&ldsW[boff + ks * 32], acc, 0, 0, 0);
            const int n = c * 32 + nt * 16 + mloc;
            const float bias = half ? 0.f : b1[k * 256 + n];
#pragma unroll
            for (int r = 0; r < 4; ++r) {
                int row = w * 16 + quad * 4 + r;
                if (half) {
                    dst[((size_t)((k * 8 + c) * 2048 + b * 64 + row)) * 32 + nt * 16 + mloc]
                        = f2bf(acc[r] + bias);
                } else {
                    dst[((size_t)(k * 2048 + b * 64 + row)) * 256 + n] = f2bf(acc[r] + bias);
                }
            }
        }
    }
}

// ---------------- edge kernel: per-kT staged H + 2-slot reg pipelining (R16/R17-proven) ----------------
__global__ __launch_bounds__(256, 3) void edge12_kernel(
    const u16* __restrict__ R, const u16* __restrict__ S2,
    const float* __restrict__ rel, const u16* __restrict__ W2t,
    const float* __restrict__ b2, u16* __restrict__ aggb)
{
    __shared__ u16   Hs[32][64][8];   // H tile for one kT: [g=kk-group][row][8kk] — 32KB
    __shared__ float Rf[4][256];      // receiver R rows, f32 — written once
    __shared__ float rtS[4][64];      // rel_type [k][j], self=0 — written once

    const int tid  = threadIdx.x;
    const int lane = tid & 63;
    const int w    = tid >> 6;        // n-quarter (MFMA) AND kk32-subgroup (build)
    const int l31  = lane & 31;
    const int lh   = lane >> 5;
    const int bid  = ((blockIdx.x & 7) << 8) | (blockIdx.x >> 3);
    const int b    = bid >> 6;
    const int i    = bid & 63;        // receiver node

    {
        const int k = tid >> 6, j = tid & 63;
        float v = 0.f;
        if (j != i) v = rel[((size_t)(b * E_) + i * 63 + (j - (j > i))) * 4 + k];
        rtS[k][j] = v;
    }
    {
        const int k = tid >> 6, e4 = tid & 63;
        u16x4 t4 = *(const u16x4*)&R[((size_t)(k * 2048 + b * 64 + i)) * 256 + e4 * 4];
#pragma unroll
        for (int e = 0; e < 4; ++e) Rf[k][e4 * 4 + e] = bf2f(t4[e]);
    }

    u16x8 sreg[8];
#pragma unroll
    for (int s = 0; s < 8; ++s)
        sreg[s] = *(const u16x8*)&S2[((size_t)(s * 2048 + b * 64 + lane)) * 32 + w * 8];

    __syncthreads();

    const u16* Wb = W2t + lh * 2048 + (w * 64 + l31) * 8;

    float amsg[2] = {0.f, 0.f};

    for (int kT = 0; kT < 4; ++kT) {
        bf16x8 Bb[2][2][2];   // [kc parity][ks2][nt] — all indices static
#pragma unroll
        for (int ks2 = 0; ks2 < 2; ++ks2) {
            const u16* wp = Wb + (size_t)(kT * 8) * 8192 + ks2 * 4096;
            Bb[0][ks2][0] = *(const bf16x8*)(wp);
            Bb[0][ks2][1] = *(const bf16x8*)(wp + 256);
        }
        // ---- build H(kT) from sreg: pure VALU, conflict-free writes ----
#pragma unroll
        for (int s = 0; s < 8; ++s) {
            const float* rp = &Rf[kT][s * 32 + w * 8];
            f32x4 r0 = *(const f32x4*)rp, r1 = *(const f32x4*)(rp + 4);
            bf16x8 o;
#pragma unroll
            for (int e = 0; e < 4; ++e) {
                o[e]     = (__bf16)fmaxf(r0[e] + bf2f(sreg[s][e]),     0.f);
                o[4 + e] = (__bf16)fmaxf(r1[e] + bf2f(sreg[s][4 + e]), 0.f);
            }
            *(bf16x8*)&Hs[s * 4 + w][lane][0] = o;
        }
        __syncthreads();   // H(kT) visible

        f32x16 acc[2][2];
#pragma unroll
        for (int mt = 0; mt < 2; ++mt)
#pragma unroll
            for (int nt = 0; nt < 2; ++nt) acc[mt][nt] = (f32x16)(0.f);

#pragma unroll
        for (int kc = 0; kc < 8; ++kc) {
            const int cur = kc & 1, nxt = cur ^ 1;
            // reload sreg for kT+1 (regs dead after the build consumed them)
            if (kc == 0 && kT < 3) {
#pragma unroll
                for (int s = 0; s < 8; ++s)
                    sreg[s] = *(const u16x8*)&S2[((size_t)(((kT + 1) * 8 + s) * 2048 + b * 64 + lane)) * 32 + w * 8];
            }
            // prefetch B(kc+1)
            if (kc < 7) {
#pragma unroll
                for (int ks2 = 0; ks2 < 2; ++ks2) {
                    const u16* wp = Wb + (size_t)(kT * 8 + kc + 1) * 8192 + ks2 * 4096;
                    Bb[nxt][ks2][0] = *(const bf16x8*)(wp);
                    Bb[nxt][ks2][1] = *(const bf16x8*)(wp + 256);
                }
            }
#pragma unroll
            for (int ks2 = 0; ks2 < 2; ++ks2) {
                const int g = kc * 4 + ks2 * 2 + lh;
                bf16x8 A0 = *(const bf16x8*)&Hs[g][l31][0];
                bf16x8 A1 = *(const bf16x8*)&Hs[g][32 + l31][0];
                acc[0][0] = __builtin_amdgcn_mfma_f32_32x32x16_bf16(A0, Bb[cur][ks2][0], acc[0][0], 0, 0, 0);
                acc[0][1] = __builtin_amdgcn_mfma_f32_32x32x16_bf16(A0, Bb[cur][ks2][1], acc[0][1], 0, 0, 0);
                acc[1][0] = __builtin_amdgcn_mfma_f32_32x32x16_bf16(A1, Bb[cur][ks2][0], acc[1][0], 0, 0, 0);
                acc[1][1] = __builtin_amdgcn_mfma_f32_32x32x16_bf16(A1, Bb[cur][ks2][1], acc[1][1], 0, 0, 0);
            }
        }

#pragma unroll
        for (int nt = 0; nt < 2; ++nt) {
            const float bias = b2[kT * 256 + w * 64 + nt * 32 + l31];
#pragma unroll
            for (int mt = 0; mt < 2; ++mt) {
                float s = 0.f;
#pragma unroll
                for (int rq = 0; rq < 4; ++rq) {
                    f32x4 rt4 = *(const f32x4*)&rtS[kT][mt * 32 + rq * 8 + 4 * lh];
#pragma unroll
                    for (int e = 0; e < 4; ++e) {
                        float v = acc[mt][nt][rq * 4 + e] + bias;
                        v = v > 0.f ? v : 0.f;
                        s += rt4[e] * v;
                    }
                }
                amsg[nt] += s;
            }
        }
        __syncthreads();
    }

#pragma unroll
    for (int nt = 0; nt < 2; ++nt) {
        float s = amsg[nt] + __shfl_xor(amsg[nt], 32);
        if (lh == 0)
            aggb[(size_t)(b * 64 + i) * 256 + w * 64 + nt * 32 + l31] = f2bf(s);
    }
}

// ---------------- output MLP: 256 blocks x 8 rows, barrier-free layers ----------------
// Dup-row trick: A rows 8..15 duplicate rows 0..7, only quad<2 writes.
__global__ __launch_bounds__(256) void outmlp6_kernel(
    const float* __restrict__ x, const u16* __restrict__ aggb,
    const float* __restrict__ Wo1, const float* __restrict__ bo1,
    const float* __restrict__ Wo2, const float* __restrict__ bo2,
    const float* __restrict__ Wo3, const float* __restrict__ bo3,
    float* __restrict__ out)
{
    __shared__ u16 p1S[8 * 264];
    __shared__ u16 p2S[8 * 264];
    const int tid = threadIdx.x, lane = tid & 63, w = tid >> 6;   // w = n-quarter
    const int quad = lane >> 4, mloc = lane & 15;
    const int row0 = blockIdx.x * 8;
    const int arow = row0 + (mloc & 7);    // duplicated A row

    {   // ---- L1: K=384 (12 chunks), N=256, aug=[x|agg] ----
        f32x4 acc[4];
#pragma unroll
        for (int nt = 0; nt < 4; ++nt) acc[nt] = (f32x4){0.f, 0.f, 0.f, 0.f};
        for (int kk = 0; kk < 12; ++kk) {
            bf16x8 aF;
            if (kk < 4) {
                u16x8 t;
#pragma unroll
                for (int e = 0; e < 8; ++e) t[e] = f2bf(x[arow * 128 + kk * 32 + quad * 8 + e]);
                __builtin_memcpy(&aF, &t, 16);
            } else {
                aF = *(const bf16x8*)&aggb[(size_t)arow * 256 + (kk - 4) * 32 + quad * 8];
            }
#pragma unroll
            for (int nt = 0; nt < 4; ++nt) {
                const int n = w * 64 + nt * 16 + mloc;
                u16x8 t;
#pragma unroll
                for (int e = 0; e < 8; ++e)
                    t[e] = f2bf(Wo1[(kk * 32 + quad * 8 + e) * 256 + n]);
                bf16x8 bF;
                __builtin_memcpy(&bF, &t, 16);
                acc[nt] = __builtin_amdgcn_mfma_f32_16x16x32_bf16(aF, bF, acc[nt], 0, 0, 0);
            }
        }
#pragma unroll
        for (int nt = 0; nt < 4; ++nt) {
            const int n = w * 64 + nt * 16 + mloc;
            const float bias = bo1[n];
            if (quad < 2) {
#pragma unroll
                for (int r = 0; r < 4; ++r) {
                    float v = acc[nt][r] + bias;
                    p1S[(quad * 4 + r) * 264 + n] = f2bf(v > 0.f ? v : 0.f);
                }
            }
        }
    }
    LBAR();
    {   // ---- L2: K=256 (8 chunks), N=256 ----
        f32x4 acc[4];
#pragma unroll
        for (int nt = 0; nt < 4; ++nt) acc[nt] = (f32x4){0.f, 0.f, 0.f, 0.f};
        for (int kk = 0; kk < 8; ++kk) {
            bf16x8 aF = *(const bf16x8*)&p1S[(mloc & 7) * 264 + kk * 32 + quad * 8];
#pragma unroll
            for (int nt = 0; nt < 4; ++nt) {
                const int n = w * 64 + nt * 16 + mloc;
                u16x8 t;
#pragma unroll
                for (int e = 0; e < 8; ++e)
                    t[e] = f2bf(Wo2[(kk * 32 + quad * 8 + e) * 256 + n]);
                bf16x8 bF;
                __builtin_memcpy(&bF, &t, 16);
                acc[nt] = __builtin_amdgcn_mfma_f32_16x16x32_bf16(aF, bF, acc[nt], 0, 0, 0);
            }
        }
#pragma unroll
        for (int nt = 0; nt < 4; ++nt) {
            const int n = w * 64 + nt * 16 + mloc;
            const float bias = bo2[n];
            if (quad < 2) {
#pragma unroll
                for (int r = 0; r < 4; ++r) {
                    float v = acc[nt][r] + bias;
                    p2S[(quad * 4 + r) * 264 + n] = f2bf(v > 0.f ? v : 0.f);
                }
            }
        }
    }
    LBAR();
    {   // ---- L3: K=256 (8 chunks), N=128, residual ----
        f32x4 acc[2];
#pragma unroll
        for (int nt = 0; nt < 2; ++nt) acc[nt] = (f32x4){0.f, 0.f, 0.f, 0.f};
        for (int kk = 0; kk < 8; ++kk) {
            bf16x8 aF = *(const bf16x8*)&p2S[(mloc & 7) * 264 + kk * 32 + quad * 8];
#pragma unroll
            for (int nt = 0; nt < 2; ++nt) {
                const int n = w * 32 + nt * 16 + mloc;
                u16x8 t;
#pragma unroll
                for (int e = 0; e < 8; ++e)
                    t[e] = f2bf(Wo3[(kk * 32 + quad * 8 + e) * 128 + n]);
                bf16x8 bF;
                __builtin_memcpy(&bF, &t, 16);
                acc[nt] = __builtin_amdgcn_mfma_f32_16x16x32_bf16(aF, bF, acc[nt], 0, 0, 0);
            }
        }
#pragma unroll
        for (int nt = 0; nt < 2; ++nt) {
            const int n = w * 32 + nt * 16 + mloc;
            const float bias = bo3[n];
            if (quad < 2) {
#pragma unroll
                for (int r = 0; r < 4; ++r) {
                    const int grow = row0 + quad * 4 + r;
                    out[grow * 128 + n] = x[grow * 128 + n] + acc[nt][r] + bias;
                }
            }
        }
    }
}

extern "C" void kernel_launch(void* const* d_in, const int* in_sizes, int n_in,
                              void* d_out, int out_size, void* d_ws, size_t ws_size,
                              hipStream_t stream) {
    const float* x   = (const float*)d_in[0];
    const float* rel = (const float*)d_in[1];
    const float* W1  = (const float*)d_in[4];
    const float* b1  = (const float*)d_in[5];
    const float* W2  = (const float*)d_in[6];
    const float* b2  = (const float*)d_in[7];
    const float* Wo1 = (const float*)d_in[8];
    const float* bo1 = (const float*)d_in[9];
    const float* Wo2 = (const float*)d_in[10];
    const float* bo2 = (const float*)d_in[11];
    const float* Wo3 = (const float*)d_in[12];
    const float* bo3 = (const float*)d_in[13];
    float* out = (float*)d_out;

    char* ws = (char*)d_ws;
    u16* W2t  = (u16*)(ws + WS_W2T);
    u16* R    = (u16*)(ws + WS_R);
    u16* S2   = (u16*)(ws + WS_S);
    u16* aggb = (u16*)(ws + WS_AGG);

    prep_rs_kernel<<<2048, 256, 0, stream>>>(W2, x, W1, b1, W2t, R, S2);
    edge12_kernel<<<2048, 256, 0, stream>>>(R, S2, rel, W2t, b2, aggb);
    outmlp6_kernel<<<256, 256, 0, stream>>>(x, aggb, Wo1, bo1, Wo2, bo2, Wo3, bo3, out);
}